// Round 5
// baseline (62.441 us; speedup 1.0000x reference)
//
#include <hip/hip_runtime.h>
#include <hip/hip_bf16.h>

#define NUM_OPS 8
#define D 1024
#define B_ROWS 8192

typedef unsigned short ushort_t;
typedef __attribute__((ext_vector_type(8))) short bf16x8;
typedef __attribute__((ext_vector_type(4))) float f32x4;
typedef __attribute__((ext_vector_type(4))) float float4v;
typedef __attribute__((ext_vector_type(8))) unsigned short ushort8;

__device__ __forceinline__ unsigned short f2bf(float f) {
    union { float f; unsigned int u; } v; v.f = f;
    unsigned int u = v.u;
    unsigned int lsb = (u >> 16) & 1u;
    u += 0x7fffu + lsb;   // round-to-nearest-even
    return (unsigned short)(u >> 16);
}

__device__ __forceinline__ void load_lds16(const void* g, void* l) {
    __builtin_amdgcn_global_load_lds(
        (const __attribute__((address_space(1))) void*)g,
        (__attribute__((address_space(3))) void*)l,
        16, 0, 0);
}

// ---------------- top-2 selection ----------------
__global__ void topk_kernel(const float* __restrict__ logits, int* __restrict__ idx) {
    if (threadIdx.x == 0 && blockIdx.x == 0) {
        float best = -__builtin_inff(); int bi = 0;
        for (int i = 0; i < NUM_OPS; ++i) {
            float v = logits[i];
            if (v > best) { best = v; bi = i; }
        }
        float best2 = -__builtin_inff(); int bi2 = 0;
        for (int i = 0; i < NUM_OPS; ++i) {
            if (i == bi) continue;
            float v = logits[i];
            if (v > best2) { best2 = v; bi2 = i; }
        }
        idx[0] = bi; idx[1] = bi2;
    }
}

// ---------------- x : f32 -> bf16 ----------------
__global__ void convert_x(const float* __restrict__ x, ushort_t* __restrict__ xb) {
    int i = (blockIdx.x * 256 + threadIdx.x) * 8;
    float4v v0 = *(const float4v*)(x + i);
    float4v v1 = *(const float4v*)(x + i + 4);
    ushort8 o;
    o[0] = f2bf(v0[0]); o[1] = f2bf(v0[1]); o[2] = f2bf(v0[2]); o[3] = f2bf(v0[3]);
    o[4] = f2bf(v1[0]); o[5] = f2bf(v1[1]); o[6] = f2bf(v1[2]); o[7] = f2bf(v1[3]);
    *(ushort8*)(xb + i) = o;
}

// ------- gather selected experts' W into MFMA-fragment-ordered bf16 --------
// Element (expert e, out-col n, k) lives at:
//   fi = (((e*32 + n>>5)*16 + k>>6)*2 + (k>>5)&1)*2 + (n>>4)&1
//   Wf[fi*512 + lane*8 + (k&7)],  lane = ((k>>3)&3)*16 + (n&15)
// so a wave's B-frag load is one coalesced 16B/lane global_load_dwordx4.
__global__ void gather_frag_W(const float* __restrict__ Ws,
                              const int* __restrict__ idx,
                              ushort_t* __restrict__ Wf) {
    __shared__ float t[32][33];
    const int b  = blockIdx.x;              // ((e*32 + kt)*32 + nt)
    const int nt = b & 31, kt = (b >> 5) & 31, e = b >> 10;
    const int td = kt * 32, te = nt * 32;
    const int tx = threadIdx.x & 31, ty = threadIdx.x >> 5;
    const float* W = Ws + (size_t)idx[e] * D * D;
    #pragma unroll
    for (int r = 0; r < 4; ++r)
        t[ty + 8 * r][tx] = W[(size_t)(td + ty + 8 * r) * D + te + tx];
    __syncthreads();
    const int vid = threadIdx.x;
    if (vid < 128) {
        const int n_l = vid & 31, kg = vid >> 5;
        const int n = te + n_l, k0 = td + kg * 8;
        const int u = k0 >> 6, kk = (k0 >> 5) & 1, lq = (k0 >> 3) & 3;
        const int p = n >> 5, n16 = (n >> 4) & 1, l15 = n & 15;
        const int lane = lq * 16 + l15;
        const int fi = (((e * 32 + p) * 16 + u) * 2 + kk) * 2 + n16;
        ushort8 o;
        #pragma unroll
        for (int j = 0; j < 8; ++j) o[j] = f2bf(t[kg * 8 + j][n_l]);
        *(ushort8*)(Wf + (size_t)fi * 512 + lane * 8) = o;
    }
}

// -------- A staging: linear LDS dest, inverse-swizzled global source --------
// LDS tile [128 rows][64 cols] bf16; LDS byte (r*128+c') holds global col
// byte (c' ^ ((r&7)<<4)).
__device__ __forceinline__ void stageA128(const ushort_t* __restrict__ Abf,
                                          int brow, int u, ushort_t* dst,
                                          int tid, int wv) {
    #pragma unroll
    for (int it = 0; it < 4; ++it) {
        const int c   = it * 256 + tid;
        const int rr  = c >> 3;
        const int cb  = (c & 7) * 16;
        const int gcb = cb ^ ((rr & 7) << 4);
        const ushort_t* g = Abf + (size_t)(brow + rr) * D + u * 64 + (gcb >> 1);
        ushort_t* l = dst + (it * 256 + wv * 64) * 8;   // bytes/2
        load_lds16(g, l);
    }
}

#define SB()     __builtin_amdgcn_sched_barrier(0)
#define BAR()    do { __builtin_amdgcn_s_barrier(); SB(); } while (0)
#define LGKM(N)  do { asm volatile("s_waitcnt lgkmcnt(" #N ")" ::: "memory"); SB(); } while (0)
#define VM(N)    do { asm volatile("s_waitcnt vmcnt(" #N ")" ::: "memory"); SB(); } while (0)
#define PRIO1()  __builtin_amdgcn_s_setprio(1)
#define PRIO0()  __builtin_amdgcn_s_setprio(0)

// ---------------- fused dual-expert GEMM, occupancy-first ------------------
// Block: 128 rows x 64 phys cols x 2 experts, 4 waves (2M x 2N), BK=64.
// Wave: 64 rows x 32 cols x 2 experts -> acc = 16 x f32x4 = 64 VGPR.
// A: LDS double-buffered (32 KB, swizzled, global_load_lds w16).
// B: direct global->VGPR from fragment-ordered Wf (coalesced dwordx4).
__global__ __launch_bounds__(256, 3)
void gemm_dual(const ushort_t* __restrict__ Abf, const ushort_t* __restrict__ Wf,
               const float* __restrict__ bs, const int* __restrict__ idx,
               float* __restrict__ out) {
    constexpr int NT = D / 64;   // 16 K-tiles
    __shared__ __align__(16) ushort_t ldsA[2][128 * 64];   // 32 KB

    const int tid  = threadIdx.x;
    const int wv   = tid >> 6;
    const int lane = tid & 63;
    const int wr   = wv >> 1, wc = wv & 1;
    const int l15  = lane & 15, lq = lane >> 4;
    const int swz  = (lane & 7) << 4;
    const int x0   = (lq * 16) ^ swz;
    const int x1   = (64 + lq * 16) ^ swz;

    // rows vary fastest across bids -> XCD x keeps row-panels {x, x+8, ...}
    // L2-resident (2 MB) across all 16 col-rounds; B panel 256 KB shared.
    const int bid     = blockIdx.x;
    const int brow    = (bid & 63) * 128;
    const int bcolIdx = bid >> 6;          // 0..15
    const int p       = bcolIdx * 2 + wc;  // 32-col panel of this wave

    f32x4  acc[2][4][2] = {};
    bf16x8 af[2][4];          // [kk][m]
    bf16x8 bfrag[2][2][2];    // [e][kk][n16]

    stageA128(Abf, brow, 0, ldsA[0], tid, wv);

    for (int u = 0; u < NT; ++u) {
        VM(0);               // my stage(u) loads landed
        BAR();               // all waves' stage(u) landed
        const char* curA = (const char*)ldsA[u & 1];

        // A fragments: 8 x ds_read_b128 (swizzled, conflict-free)
        #pragma unroll
        for (int kk = 0; kk < 2; ++kk)
            #pragma unroll
            for (int m = 0; m < 4; ++m)
                af[kk][m] = *(const bf16x8*)(curA +
                    (size_t)((wr * 64 + m * 16 + l15) * 128) + (kk ? x1 : x0));

        // B fragments: 8 x global_load_dwordx4, coalesced from Wf
        #pragma unroll
        for (int e = 0; e < 2; ++e)
            #pragma unroll
            for (int kk = 0; kk < 2; ++kk)
                #pragma unroll
                for (int n16 = 0; n16 < 2; ++n16) {
                    const int fi = (((e * 32 + p) * 16 + u) * 2 + kk) * 2 + n16;
                    bfrag[e][kk][n16] = *(const bf16x8*)(Wf + (size_t)fi * 512 + lane * 8);
                }

        if (u + 1 < NT)
            stageA128(Abf, brow, u + 1, ldsA[(u + 1) & 1], tid, wv);

        LGKM(0);             // A frags in regs
        if (u + 1 < NT) { VM(4); }   // B(u) done; stage(u+1) stays in flight
        else            { VM(0); }

        PRIO1();
        #pragma unroll
        for (int kk = 0; kk < 2; ++kk)
            #pragma unroll
            for (int e = 0; e < 2; ++e)
                #pragma unroll
                for (int m = 0; m < 4; ++m)
                    #pragma unroll
                    for (int n16 = 0; n16 < 2; ++n16)
                        acc[e][m][n16] = __builtin_amdgcn_mfma_f32_16x16x32_bf16(
                            af[kk][m], bfrag[e][kk][n16], acc[e][m][n16], 0, 0, 0);
        PRIO0();
    }

    // ---- epilogue: per-expert bias + relu, sum, store f32
    const int i0 = idx[0], i1 = idx[1];
    #pragma unroll
    for (int n16 = 0; n16 < 2; ++n16) {
        const int col = bcolIdx * 64 + wc * 32 + n16 * 16 + l15;
        const float b0 = bs[i0 * D + col];
        const float b1 = bs[i1 * D + col];
        #pragma unroll
        for (int m = 0; m < 4; ++m) {
            const int rbase = brow + wr * 64 + m * 16 + lq * 4;
            #pragma unroll
            for (int i = 0; i < 4; ++i) {
                float v0 = acc[0][m][n16][i] + b0; v0 = v0 > 0.f ? v0 : 0.f;
                float v1 = acc[1][m][n16][i] + b1; v1 = v1 > 0.f ? v1 : 0.f;
                out[(size_t)(rbase + i) * D + col] = v0 + v1;
            }
        }
    }
}

extern "C" void kernel_launch(void* const* d_in, const int* in_sizes, int n_in,
                              void* d_out, int out_size, void* d_ws, size_t ws_size,
                              hipStream_t stream) {
    const float* x      = (const float*)d_in[0];
    const float* logits = (const float*)d_in[1];
    const float* Ws     = (const float*)d_in[2];
    const float* bs     = (const float*)d_in[3];
    float* out = (float*)d_out;

    char* ws = (char*)d_ws;
    ushort_t* xbf = (ushort_t*)ws;                                   // 16 MB
    ushort_t* Wf  = (ushort_t*)(ws + (size_t)B_ROWS * D * 2);        //  4 MB
    int* idx      = (int*)(ws + (size_t)B_ROWS * D * 2 + (size_t)2 * D * D * 2);

    topk_kernel<<<1, 1, 0, stream>>>(logits, idx);
    convert_x<<<(B_ROWS * D) / (256 * 8), 256, 0, stream>>>(x, xbf);
    gather_frag_W<<<2 * 32 * 32, 256, 0, stream>>>(Ws, idx, Wf);

    gemm_dual<<<1024, 256, 0, stream>>>(xbf, Wf, bs, idx, out);
}

// Round 6
// 61.126 us; speedup vs baseline: 1.0215x; 1.0215x over previous
//
#include <hip/hip_runtime.h>
#include <hip/hip_bf16.h>

#define NUM_OPS 8
#define D 1024
#define B_ROWS 8192

typedef unsigned short ushort_t;
typedef __attribute__((ext_vector_type(8))) short bf16x8;
typedef __attribute__((ext_vector_type(4))) float f32x4;
typedef __attribute__((ext_vector_type(4))) float float4v;
typedef __attribute__((ext_vector_type(8))) unsigned short ushort8;

__device__ __forceinline__ unsigned short f2bf(float f) {
    union { float f; unsigned int u; } v; v.f = f;
    unsigned int u = v.u;
    unsigned int lsb = (u >> 16) & 1u;
    u += 0x7fffu + lsb;   // round-to-nearest-even
    return (unsigned short)(u >> 16);
}

// ---------------- top-2 selection ----------------
__global__ void topk_kernel(const float* __restrict__ logits, int* __restrict__ idx) {
    if (threadIdx.x == 0 && blockIdx.x == 0) {
        float best = -__builtin_inff(); int bi = 0;
        for (int i = 0; i < NUM_OPS; ++i) {
            float v = logits[i];
            if (v > best) { best = v; bi = i; }
        }
        float best2 = -__builtin_inff(); int bi2 = 0;
        for (int i = 0; i < NUM_OPS; ++i) {
            if (i == bi) continue;
            float v = logits[i];
            if (v > best2) { best2 = v; bi2 = i; }
        }
        idx[0] = bi; idx[1] = bi2;
    }
}

// -------- x: f32 -> bf16, reordered into MFMA A-fragment layout ------------
// AFI(r,u,kk,m) = (r*16+u)*8 + kk*4 + m    (r:0..127 row-block, u:0..15 K-tile)
// Af[AFI*512 + lane*8 + j] = x[r*64 + m*16 + (lane&15)][u*64 + kk*32 + (lane>>4)*8 + j]
// => a wave's 8 A-frags for tile u are one contiguous 8KB block, 1KB coalesced each.
__global__ void convert_frag_x(const float* __restrict__ x, ushort_t* __restrict__ Af) {
    __shared__ float t[64][65];
    const int b = blockIdx.x;            // r*16 + u
    const int r = b >> 4, u = b & 15;
    const int tid = threadIdx.x;

    // load 64x64 f32 tile, coalesced (4 threads x 16 floats per row)
    const int row = tid >> 2, c0 = (tid & 3) * 16;
    const float* src = x + (size_t)(r * 64 + row) * D + u * 64 + c0;
    #pragma unroll
    for (int j = 0; j < 4; ++j) {
        float4v v = *(const float4v*)(src + j * 4);
        t[row][c0 + j * 4 + 0] = v[0];
        t[row][c0 + j * 4 + 1] = v[1];
        t[row][c0 + j * 4 + 2] = v[2];
        t[row][c0 + j * 4 + 3] = v[3];
    }
    __syncthreads();

    // write 512 lane-groups (8 frags x 64 lanes), 2 per thread
    #pragma unroll
    for (int g2 = 0; g2 < 2; ++g2) {
        const int g = g2 * 256 + tid;
        const int f = g >> 6, lane = g & 63;     // f = kk*4 + m
        const int kk = f >> 2, m = f & 3;
        const int rr = m * 16 + (lane & 15);
        const int cc = kk * 32 + (lane >> 4) * 8;
        ushort8 o;
        #pragma unroll
        for (int j = 0; j < 8; ++j) o[j] = f2bf(t[rr][cc + j]);
        *(ushort8*)(Af + ((size_t)(r * 16 + u) * 8 + f) * 512 + lane * 8) = o;
    }
}

// ------- gather selected experts' W into MFMA B-fragment layout ------------
// fi = (((e*32 + p)*16 + u)*2 + kk)*2 + n16 ; Wf[fi*512 + lane*8 + j] =
//   W[u*64 + kk*32 + (lane>>4)*8 + j][p*32 + n16*16 + (lane&15)]
__global__ void gather_frag_W(const float* __restrict__ Ws,
                              const int* __restrict__ idx,
                              ushort_t* __restrict__ Wf) {
    __shared__ float t[32][33];
    const int b  = blockIdx.x;              // ((e*32 + kt)*32 + nt)
    const int nt = b & 31, kt = (b >> 5) & 31, e = b >> 10;
    const int td = kt * 32, te = nt * 32;
    const int tx = threadIdx.x & 31, ty = threadIdx.x >> 5;
    const float* W = Ws + (size_t)idx[e] * D * D;
    #pragma unroll
    for (int r = 0; r < 4; ++r)
        t[ty + 8 * r][tx] = W[(size_t)(td + ty + 8 * r) * D + te + tx];
    __syncthreads();
    const int vid = threadIdx.x;
    if (vid < 128) {
        const int n_l = vid & 31, kg = vid >> 5;
        const int n = te + n_l, k0 = td + kg * 8;
        const int u = k0 >> 6, kk = (k0 >> 5) & 1, lq = (k0 >> 3) & 3;
        const int p = n >> 5, n16 = (n >> 4) & 1, l15 = n & 15;
        const int lane = lq * 16 + l15;
        const int fi = (((e * 32 + p) * 16 + u) * 2 + kk) * 2 + n16;
        ushort8 o;
        #pragma unroll
        for (int j = 0; j < 8; ++j) o[j] = f2bf(t[kg * 8 + j][n_l]);
        *(ushort8*)(Wf + (size_t)fi * 512 + lane * 8) = o;
    }
}

// ---------------- fused dual-expert GEMM: no LDS, no barriers --------------
// 4 independent waves per block. Wave tile: 64 rows x 32 cols x 2 experts.
// Per K-tile: 8 coalesced A-frag loads (contiguous 8KB) + 8 B-frag loads +
// 32 MFMA. Compiler pipelines with counted vmcnt; TLP across waves hides
// the rest. acc = 64 VGPR.
__global__ __launch_bounds__(256, 2)
void gemm_frag(const ushort_t* __restrict__ Af, const ushort_t* __restrict__ Wf,
               const float* __restrict__ bs, const int* __restrict__ idx,
               float* __restrict__ out) {
    const int tid  = threadIdx.x;
    const int wv   = tid >> 6;
    const int lane = tid & 63;
    const int l15  = lane & 15, lq = lane >> 4;

    const int Wg = blockIdx.x * 4 + wv;     // 0..4095
    const int r  = Wg & 127;                // row-block (64 rows)
    const int p  = Wg >> 7;                 // 32-col panel (0..31)

    f32x4 acc[2][4][2] = {};

    const ushort_t* Abase = Af + (size_t)r * 16 * 8 * 512 + lane * 8;
    const ushort_t* Bbase = Wf + lane * 8;

    for (int u = 0; u < 16; ++u) {
        bf16x8 a[2][4], b[2][2][2];
        #pragma unroll
        for (int kk = 0; kk < 2; ++kk)
            #pragma unroll
            for (int m = 0; m < 4; ++m)
                a[kk][m] = *(const bf16x8*)(Abase + (size_t)(u * 8 + kk * 4 + m) * 512);
        #pragma unroll
        for (int e = 0; e < 2; ++e)
            #pragma unroll
            for (int kk = 0; kk < 2; ++kk)
                #pragma unroll
                for (int n16 = 0; n16 < 2; ++n16) {
                    const int fi = (((e * 32 + p) * 16 + u) * 2 + kk) * 2 + n16;
                    b[e][kk][n16] = *(const bf16x8*)(Bbase + (size_t)fi * 512);
                }
        #pragma unroll
        for (int kk = 0; kk < 2; ++kk)
            #pragma unroll
            for (int e = 0; e < 2; ++e)
                #pragma unroll
                for (int m = 0; m < 4; ++m)
                    #pragma unroll
                    for (int n16 = 0; n16 < 2; ++n16)
                        acc[e][m][n16] = __builtin_amdgcn_mfma_f32_16x16x32_bf16(
                            a[kk][m], b[e][kk][n16], acc[e][m][n16], 0, 0, 0);
    }

    // ---- epilogue: per-expert bias + relu, sum, store f32
    const int i0 = idx[0], i1 = idx[1];
    #pragma unroll
    for (int n16 = 0; n16 < 2; ++n16) {
        const int col = p * 32 + n16 * 16 + l15;
        const float b0 = bs[i0 * D + col];
        const float b1 = bs[i1 * D + col];
        #pragma unroll
        for (int m = 0; m < 4; ++m) {
            const int rbase = r * 64 + m * 16 + lq * 4;
            #pragma unroll
            for (int i = 0; i < 4; ++i) {
                float v0 = acc[0][m][n16][i] + b0; v0 = v0 > 0.f ? v0 : 0.f;
                float v1 = acc[1][m][n16][i] + b1; v1 = v1 > 0.f ? v1 : 0.f;
                out[(size_t)(rbase + i) * D + col] = v0 + v1;
            }
        }
    }
}

extern "C" void kernel_launch(void* const* d_in, const int* in_sizes, int n_in,
                              void* d_out, int out_size, void* d_ws, size_t ws_size,
                              hipStream_t stream) {
    const float* x      = (const float*)d_in[0];
    const float* logits = (const float*)d_in[1];
    const float* Ws     = (const float*)d_in[2];
    const float* bs     = (const float*)d_in[3];
    float* out = (float*)d_out;

    char* ws = (char*)d_ws;
    ushort_t* Af = (ushort_t*)ws;                                    // 16 MB
    ushort_t* Wf = (ushort_t*)(ws + (size_t)B_ROWS * D * 2);         //  4 MB
    int* idx     = (int*)(ws + (size_t)B_ROWS * D * 2 + (size_t)2 * D * D * 2);

    topk_kernel<<<1, 1, 0, stream>>>(logits, idx);
    convert_frag_x<<<128 * 16, 256, 0, stream>>>(x, Af);
    gather_frag_W<<<2 * 32 * 32, 256, 0, stream>>>(Ws, idx, Wf);

    gemm_frag<<<1024, 256, 0, stream>>>(Af, Wf, bs, idx, out);
}

// Round 7
// 59.442 us; speedup vs baseline: 1.0505x; 1.0283x over previous
//
#include <hip/hip_runtime.h>
#include <hip/hip_bf16.h>

#define NUM_OPS 8
#define D 1024
#define B_ROWS 8192

typedef unsigned short ushort_t;
typedef __attribute__((ext_vector_type(8))) short bf16x8;
typedef __attribute__((ext_vector_type(4))) float f32x4;
typedef __attribute__((ext_vector_type(4))) float float4v;
typedef __attribute__((ext_vector_type(8))) unsigned short ushort8;

__device__ __forceinline__ unsigned short f2bf(float f) {
    union { float f; unsigned int u; } v; v.f = f;
    unsigned int u = v.u;
    unsigned int lsb = (u >> 16) & 1u;
    u += 0x7fffu + lsb;   // round-to-nearest-even
    return (unsigned short)(u >> 16);
}

// ---------------- top-2 selection ----------------
__global__ void topk_kernel(const float* __restrict__ logits, int* __restrict__ idx) {
    if (threadIdx.x == 0 && blockIdx.x == 0) {
        float best = -__builtin_inff(); int bi = 0;
        for (int i = 0; i < NUM_OPS; ++i) {
            float v = logits[i];
            if (v > best) { best = v; bi = i; }
        }
        float best2 = -__builtin_inff(); int bi2 = 0;
        for (int i = 0; i < NUM_OPS; ++i) {
            if (i == bi) continue;
            float v = logits[i];
            if (v > best2) { best2 = v; bi2 = i; }
        }
        idx[0] = bi; idx[1] = bi2;
    }
}

// -------- x: f32 -> bf16, reordered into MFMA A-fragment layout ------------
// AFI(r,u,kk,m) = (r*16+u)*8 + kk*4 + m
// Af[AFI*512 + lane*8 + j] = x[r*64 + m*16 + (lane&15)][u*64 + kk*32 + (lane>>4)*8 + j]
__global__ void convert_frag_x(const float* __restrict__ x, ushort_t* __restrict__ Af) {
    __shared__ float t[64][65];
    const int b = blockIdx.x;            // r*16 + u
    const int r = b >> 4, u = b & 15;
    const int tid = threadIdx.x;

    const int row = tid >> 2, c0 = (tid & 3) * 16;
    const float* src = x + (size_t)(r * 64 + row) * D + u * 64 + c0;
    #pragma unroll
    for (int j = 0; j < 4; ++j) {
        float4v v = *(const float4v*)(src + j * 4);
        t[row][c0 + j * 4 + 0] = v[0];
        t[row][c0 + j * 4 + 1] = v[1];
        t[row][c0 + j * 4 + 2] = v[2];
        t[row][c0 + j * 4 + 3] = v[3];
    }
    __syncthreads();

    #pragma unroll
    for (int g2 = 0; g2 < 2; ++g2) {
        const int g = g2 * 256 + tid;
        const int f = g >> 6, lane = g & 63;     // f = kk*4 + m
        const int kk = f >> 2, m = f & 3;
        const int rr = m * 16 + (lane & 15);
        const int cc = kk * 32 + (lane >> 4) * 8;
        ushort8 o;
        #pragma unroll
        for (int j = 0; j < 8; ++j) o[j] = f2bf(t[rr][cc + j]);
        *(ushort8*)(Af + ((size_t)(r * 16 + u) * 8 + f) * 512 + lane * 8) = o;
    }
}

// ------- gather selected experts' W into MFMA B-fragment layout ------------
// fi = (((e*32 + p)*16 + u)*2 + kk)*2 + n16 ; Wf[fi*512 + lane*8 + j] =
//   W[u*64 + kk*32 + (lane>>4)*8 + j][p*32 + n16*16 + (lane&15)]
__global__ void gather_frag_W(const float* __restrict__ Ws,
                              const int* __restrict__ idx,
                              ushort_t* __restrict__ Wf) {
    __shared__ float t[32][33];
    const int b  = blockIdx.x;              // ((e*32 + kt)*32 + nt)
    const int nt = b & 31, kt = (b >> 5) & 31, e = b >> 10;
    const int td = kt * 32, te = nt * 32;
    const int tx = threadIdx.x & 31, ty = threadIdx.x >> 5;
    const float* W = Ws + (size_t)idx[e] * D * D;
    #pragma unroll
    for (int r = 0; r < 4; ++r)
        t[ty + 8 * r][tx] = W[(size_t)(td + ty + 8 * r) * D + te + tx];
    __syncthreads();
    const int vid = threadIdx.x;
    if (vid < 128) {
        const int n_l = vid & 31, kg = vid >> 5;
        const int n = te + n_l, k0 = td + kg * 8;
        const int u = k0 >> 6, kk = (k0 >> 5) & 1, lq = (k0 >> 3) & 3;
        const int p = n >> 5, n16 = (n >> 4) & 1, l15 = n & 15;
        const int lane = lq * 16 + l15;
        const int fi = (((e * 32 + p) * 16 + u) * 2 + kk) * 2 + n16;
        ushort8 o;
        #pragma unroll
        for (int j = 0; j < 8; ++j) o[j] = f2bf(t[kg * 8 + j][n_l]);
        *(ushort8*)(Wf + (size_t)fi * 512 + lane * 8) = o;
    }
}

#define SB()    __builtin_amdgcn_sched_barrier(0)
#define PRIO1() __builtin_amdgcn_s_setprio(1)
#define PRIO0() __builtin_amdgcn_s_setprio(0)

// load one tile's 16 fragments into a named set (static indices only)
#define LOADSET(aS, bS, u)                                                         \
    do {                                                                           \
        _Pragma("unroll") for (int f = 0; f < 8; ++f)                              \
            aS[f] = *(const bf16x8*)(Abase + ((size_t)(u) * 8 + f) * 512);         \
        _Pragma("unroll") for (int e = 0; e < 2; ++e)                              \
        _Pragma("unroll") for (int kn = 0; kn < 4; ++kn)                           \
            bS[e * 4 + kn] = *(const bf16x8*)(Bbase +                              \
                ((size_t)(((e * 32 + p) * 16 + (u)) * 4) + kn) * 512);             \
    } while (0)

// 32 MFMA on a named set. aS index: kk*4+m ; bS index: e*4 + kk*2 + n16
#define MFMASET(aS, bS)                                                            \
    do {                                                                           \
        PRIO1();                                                                   \
        _Pragma("unroll") for (int kk = 0; kk < 2; ++kk)                           \
        _Pragma("unroll") for (int e = 0; e < 2; ++e)                              \
        _Pragma("unroll") for (int m = 0; m < 4; ++m)                              \
        _Pragma("unroll") for (int n16 = 0; n16 < 2; ++n16)                        \
            acc[e][m][n16] = __builtin_amdgcn_mfma_f32_16x16x32_bf16(              \
                aS[kk * 4 + m], bS[e * 4 + kk * 2 + n16], acc[e][m][n16], 0, 0, 0);\
        PRIO0();                                                                   \
    } while (0)

// ---------------- fused dual-expert GEMM: no LDS, explicit 2-deep pipeline --
// 4 independent waves/block (2r x 2p). Wave: 64 rows x 32 cols x 2 experts.
// Two named fragment sets; loads for tile u+1 pinned (sched_barrier) before
// MFMA of tile u -> compiler emits counted vmcnt, latency hidden by prefetch.
__global__ __launch_bounds__(256, 2)
void gemm_frag(const ushort_t* __restrict__ Af, const ushort_t* __restrict__ Wf,
               const float* __restrict__ bs, const int* __restrict__ idx,
               float* __restrict__ out) {
    const int tid  = threadIdx.x;
    const int wv   = tid >> 6;
    const int lane = tid & 63;
    const int l15  = lane & 15, lq = lane >> 4;

    // 2x2 wave arrangement: waves {0,1} share p-pair rows, {0,2} share r...
    const int r = (blockIdx.x & 63) * 2 + (wv & 1);    // 0..127 row-block
    const int p = (blockIdx.x >> 6) * 2 + (wv >> 1);   // 0..31 col-panel

    f32x4 acc[2][4][2] = {};

    const ushort_t* Abase = Af + (size_t)r * 16 * 8 * 512 + lane * 8;
    const ushort_t* Bbase = Wf + lane * 8;

    bf16x8 aS0[8], bS0[8], aS1[8], bS1[8];

    LOADSET(aS0, bS0, 0);
    SB();
    LOADSET(aS1, bS1, 1);
    SB();

    #pragma unroll 1
    for (int u = 0; u < 14; u += 2) {
        MFMASET(aS0, bS0);          // tile u (waits only its own set)
        SB();
        LOADSET(aS0, bS0, u + 2);   // prefetch depth 2
        SB();
        MFMASET(aS1, bS1);          // tile u+1
        SB();
        LOADSET(aS1, bS1, u + 3);
        SB();
    }
    MFMASET(aS0, bS0);              // tile 14
    SB();
    MFMASET(aS1, bS1);              // tile 15

    // ---- epilogue: per-expert bias + relu, sum, store f32
    const int i0 = idx[0], i1 = idx[1];
    #pragma unroll
    for (int n16 = 0; n16 < 2; ++n16) {
        const int col = p * 32 + n16 * 16 + l15;
        const float b0 = bs[i0 * D + col];
        const float b1 = bs[i1 * D + col];
        #pragma unroll
        for (int m = 0; m < 4; ++m) {
            const int rbase = r * 64 + m * 16 + lq * 4;
            #pragma unroll
            for (int i = 0; i < 4; ++i) {
                float v0 = acc[0][m][n16][i] + b0; v0 = v0 > 0.f ? v0 : 0.f;
                float v1 = acc[1][m][n16][i] + b1; v1 = v1 > 0.f ? v1 : 0.f;
                out[(size_t)(rbase + i) * D + col] = v0 + v1;
            }
        }
    }
}

extern "C" void kernel_launch(void* const* d_in, const int* in_sizes, int n_in,
                              void* d_out, int out_size, void* d_ws, size_t ws_size,
                              hipStream_t stream) {
    const float* x      = (const float*)d_in[0];
    const float* logits = (const float*)d_in[1];
    const float* Ws     = (const float*)d_in[2];
    const float* bs     = (const float*)d_in[3];
    float* out = (float*)d_out;

    char* ws = (char*)d_ws;
    ushort_t* Af = (ushort_t*)ws;                                    // 16 MB
    ushort_t* Wf = (ushort_t*)(ws + (size_t)B_ROWS * D * 2);         //  4 MB
    int* idx     = (int*)(ws + (size_t)B_ROWS * D * 2 + (size_t)2 * D * D * 2);

    topk_kernel<<<1, 1, 0, stream>>>(logits, idx);
    convert_frag_x<<<128 * 16, 256, 0, stream>>>(x, Af);
    gather_frag_W<<<2 * 32 * 32, 256, 0, stream>>>(Ws, idx, Wf);

    gemm_frag<<<1024, 256, 0, stream>>>(Af, Wf, bs, idx, out);
}